// Round 1
// baseline (238.515 us; speedup 1.0000x reference)
//
#include <hip/hip_runtime.h>
#include <math.h>

#define DIM 1024

// Kernel 1: mask = PRUNE_RATE * DIM * softmax(mask_param) * _mask
// One block of 1024 threads (16 waves). Two block reductions (max, sum).
__global__ __launch_bounds__(1024) void mask_softmax_kernel(
    const float* __restrict__ mask_param,
    const float* __restrict__ mask_in,
    float* __restrict__ mask_out)
{
    __shared__ float red[16];
    __shared__ float s_max, s_sum;
    const int t = threadIdx.x;            // 0..1023

    const float p = mask_param[t];

    // ---- block max ----
    float m = p;
    #pragma unroll
    for (int o = 32; o > 0; o >>= 1) m = fmaxf(m, __shfl_down(m, o, 64));
    if ((t & 63) == 0) red[t >> 6] = m;
    __syncthreads();
    if (t < 16) {
        float mm = red[t];
        #pragma unroll
        for (int o = 8; o > 0; o >>= 1) mm = fmaxf(mm, __shfl_down(mm, o, 16));
        if (t == 0) s_max = mm;
    }
    __syncthreads();

    // ---- block sum of exp ----
    const float e = expf(p - s_max);
    float s = e;
    #pragma unroll
    for (int o = 32; o > 0; o >>= 1) s += __shfl_down(s, o, 64);
    if ((t & 63) == 0) red[t >> 6] = s;
    __syncthreads();
    if (t < 16) {
        float ss = red[t];
        #pragma unroll
        for (int o = 8; o > 0; o >>= 1) ss += __shfl_down(ss, o, 16);
        if (t == 0) s_sum = ss;
    }
    __syncthreads();

    // PRUNE_RATE = 1.0
    mask_out[t] = (float)DIM * (e / s_sum) * mask_in[t];
}

// Kernel 2: out[i] = x[i] * mask[i % DIM], float4-vectorized.
// stride (gridDim*256) is a multiple of 256 float4 = DIM floats, so each
// thread's channel group (idx & 255) is loop-invariant -> mask in registers.
__global__ __launch_bounds__(256) void mask_mul_kernel(
    const float4* __restrict__ x,
    const float4* __restrict__ mask4,   // DIM/4 = 256 float4
    float4* __restrict__ out,
    int n4)
{
    const int idx    = blockIdx.x * 256 + threadIdx.x;
    const int stride = gridDim.x * 256;

    const float4 mv = mask4[idx & 255];

    for (int i = idx; i < n4; i += stride) {
        float4 v = x[i];
        v.x *= mv.x; v.y *= mv.y; v.z *= mv.z; v.w *= mv.w;
        out[i] = v;
    }
}

extern "C" void kernel_launch(void* const* d_in, const int* in_sizes, int n_in,
                              void* d_out, int out_size, void* d_ws, size_t ws_size,
                              hipStream_t stream)
{
    const float* x          = (const float*)d_in[0];   // [8,4096,1024] fp32
    const float* mask_param = (const float*)d_in[1];   // [1024] fp32
    const float* mask_in    = (const float*)d_in[2];   // [1024] fp32 (ones)

    const int n = in_sizes[0];                         // 8*4096*1024 = 33554432
    float* out_xm   = (float*)d_out;                   // output 0: [8,4096,1024]
    float* out_mask = (float*)d_out + n;               // output 1: [1024]

    // 1) compute mask into output-1 slot
    mask_softmax_kernel<<<1, 1024, 0, stream>>>(mask_param, mask_in, out_mask);

    // 2) broadcast multiply, float4-vectorized
    const int n4 = n / 4;                              // 8388608
    const int blocks = 4096;                           // 8 float4/thread
    mask_mul_kernel<<<blocks, 256, 0, stream>>>(
        (const float4*)x, (const float4*)out_mask, (float4*)out_xm, n4);
}

// Round 2
// 232.433 us; speedup vs baseline: 1.0262x; 1.0262x over previous
//
#include <hip/hip_runtime.h>
#include <math.h>

#define DIM 1024

// Fused kernel: every block redundantly computes
//   mask = DIM * softmax(mask_param) * _mask          (1024 channels)
// then applies its grid-stride slice of out = x * mask (float4-vectorized).
// Block 0 additionally writes the mask to the second output slot.
//
// Layout invariant: blockDim = 256, so thread t's float4 channel group is
// channels [4t, 4t+3] for every grid-stride iteration (stride is a multiple
// of 256 float4 = 1024 floats). Mask stays in 4 registers.
__global__ __launch_bounds__(256) void fused_mask_mul_kernel(
    const float4* __restrict__ x,
    const float4* __restrict__ mask_param4,  // 256 float4 = 1024 floats
    const float4* __restrict__ mask_in4,     // 256 float4
    float4* __restrict__ out,
    float4* __restrict__ mask_out4,          // 256 float4 (output 1)
    int n4)
{
    const int t = threadIdx.x;               // 0..255

    // ---- per-block softmax over 1024 channels (thread t owns 4t..4t+3) ----
    const float4 p = mask_param4[t];

    // block max
    float m = fmaxf(fmaxf(p.x, p.y), fmaxf(p.z, p.w));
    #pragma unroll
    for (int o = 32; o > 0; o >>= 1) m = fmaxf(m, __shfl_down(m, o, 64));
    __shared__ float red[4];
    __shared__ float s_max, s_sum;
    if ((t & 63) == 0) red[t >> 6] = m;
    __syncthreads();
    if (t == 0) s_max = fmaxf(fmaxf(red[0], red[1]), fmaxf(red[2], red[3]));
    __syncthreads();

    const float mx = s_max;
    float4 e;
    e.x = __expf(p.x - mx); e.y = __expf(p.y - mx);
    e.z = __expf(p.z - mx); e.w = __expf(p.w - mx);

    // block sum
    float s = e.x + e.y + e.z + e.w;
    #pragma unroll
    for (int o = 32; o > 0; o >>= 1) s += __shfl_down(s, o, 64);
    if ((t & 63) == 0) red[t >> 6] = s;
    __syncthreads();
    if (t == 0) s_sum = red[0] + red[1] + red[2] + red[3];
    __syncthreads();

    const float scale = (float)DIM / s_sum;  // PRUNE_RATE = 1.0
    const float4 mi = mask_in4[t];
    float4 mv;
    mv.x = e.x * scale * mi.x; mv.y = e.y * scale * mi.y;
    mv.z = e.z * scale * mi.z; mv.w = e.w * scale * mi.w;

    if (blockIdx.x == 0) mask_out4[t] = mv;

    // ---- grid-stride broadcast multiply ----
    const int idx    = blockIdx.x * 256 + t;
    const int stride = gridDim.x * 256;      // multiple of 256 -> mask invariant
    for (int i = idx; i < n4; i += stride) {
        float4 v = x[i];
        v.x *= mv.x; v.y *= mv.y; v.z *= mv.z; v.w *= mv.w;
        out[i] = v;
    }
}

extern "C" void kernel_launch(void* const* d_in, const int* in_sizes, int n_in,
                              void* d_out, int out_size, void* d_ws, size_t ws_size,
                              hipStream_t stream)
{
    const float* x          = (const float*)d_in[0];   // [8,4096,1024] fp32
    const float* mask_param = (const float*)d_in[1];   // [1024] fp32
    const float* mask_in    = (const float*)d_in[2];   // [1024] fp32 (ones)

    const int n = in_sizes[0];                         // 33554432
    float* out_xm   = (float*)d_out;                   // output 0
    float* out_mask = (float*)d_out + n;               // output 1 (1024 floats)

    const int n4 = n / 4;                              // 8388608
    const int blocks = 8192;                           // 4 float4 per thread
    fused_mask_mul_kernel<<<blocks, 256, 0, stream>>>(
        (const float4*)x, (const float4*)mask_param, (const float4*)mask_in,
        (float4*)out_xm, (float4*)out_mask, n4);
}

// Round 4
// 226.137 us; speedup vs baseline: 1.0547x; 1.0278x over previous
//
#include <hip/hip_runtime.h>
#include <math.h>

#define DIM 1024

// Native clang vector type — __builtin_nontemporal_load/store require a
// scalar or native vector, not HIP_vector_type<float,4>.
typedef float vfloat4 __attribute__((ext_vector_type(4)));

// Fused kernel: every block redundantly computes
//   mask = DIM * softmax(mask_param) * _mask          (1024 channels)
// then applies its grid-stride slice of out = x * mask (float4-vectorized,
// nontemporal: x/out are streamed exactly once, keep them out of L2).
// Block 0 additionally writes the mask to the second output slot.
//
// blocks=2048: 8 blocks/CU x 256 CU, 4 waves/block -> 32 waves/CU, full
// occupancy in one dispatch round; 4096 float4/block (64 KB streamed) vs
// ~8 KB redundant softmax traffic.
__global__ __launch_bounds__(256) void fused_mask_mul_kernel(
    const vfloat4* __restrict__ x,
    const vfloat4* __restrict__ mask_param4,  // 256 float4 = 1024 floats
    const vfloat4* __restrict__ mask_in4,     // 256 float4
    vfloat4* __restrict__ out,
    vfloat4* __restrict__ mask_out4,          // 256 float4 (output 1)
    int n4)
{
    const int t = threadIdx.x;               // 0..255

    // ---- per-block softmax over 1024 channels (thread t owns 4t..4t+3) ----
    const vfloat4 p = mask_param4[t];

    float m = fmaxf(fmaxf(p.x, p.y), fmaxf(p.z, p.w));
    #pragma unroll
    for (int o = 32; o > 0; o >>= 1) m = fmaxf(m, __shfl_down(m, o, 64));
    __shared__ float red[4];
    __shared__ float s_max, s_sum;
    if ((t & 63) == 0) red[t >> 6] = m;
    __syncthreads();
    if (t == 0) s_max = fmaxf(fmaxf(red[0], red[1]), fmaxf(red[2], red[3]));
    __syncthreads();

    const float mx = s_max;
    vfloat4 e;
    e.x = __expf(p.x - mx); e.y = __expf(p.y - mx);
    e.z = __expf(p.z - mx); e.w = __expf(p.w - mx);

    float s = e.x + e.y + e.z + e.w;
    #pragma unroll
    for (int o = 32; o > 0; o >>= 1) s += __shfl_down(s, o, 64);
    if ((t & 63) == 0) red[t >> 6] = s;
    __syncthreads();
    if (t == 0) s_sum = red[0] + red[1] + red[2] + red[3];
    __syncthreads();

    const float scale = (float)DIM / s_sum;  // PRUNE_RATE = 1.0
    const vfloat4 mi = mask_in4[t];
    vfloat4 mv = e * scale * mi;

    if (blockIdx.x == 0) mask_out4[t] = mv;

    // ---- grid-stride broadcast multiply, nontemporal ----
    const int idx    = blockIdx.x * 256 + t;
    const int stride = gridDim.x * 256;      // multiple of 256 -> mask invariant
    for (int i = idx; i < n4; i += stride) {
        vfloat4 v = __builtin_nontemporal_load(&x[i]);
        v *= mv;
        __builtin_nontemporal_store(v, &out[i]);
    }
}

extern "C" void kernel_launch(void* const* d_in, const int* in_sizes, int n_in,
                              void* d_out, int out_size, void* d_ws, size_t ws_size,
                              hipStream_t stream)
{
    const float* x          = (const float*)d_in[0];   // [8,4096,1024] fp32
    const float* mask_param = (const float*)d_in[1];   // [1024] fp32
    const float* mask_in    = (const float*)d_in[2];   // [1024] fp32 (ones)

    const int n = in_sizes[0];                         // 33554432
    float* out_xm   = (float*)d_out;                   // output 0
    float* out_mask = (float*)d_out + n;               // output 1 (1024 floats)

    const int n4 = n / 4;                              // 8388608
    const int blocks = 2048;                           // 16 float4 per thread
    fused_mask_mul_kernel<<<blocks, 256, 0, stream>>>(
        (const vfloat4*)x, (const vfloat4*)mask_param, (const vfloat4*)mask_in,
        (vfloat4*)out_xm, (vfloat4*)out_mask, n4);
}